// Round 8
// baseline (311.427 us; speedup 1.0000x reference)
//
#include <hip/hip_runtime.h>
#include <hip/hip_bf16.h>

// SwitchMoE: N=16384, D=512, F=2048, E=8, top-1. Sparse one-expert-per-token.
// R14: ffn2 split-K-across-waves. Cycle model on R7/R13 config: 607 cyc/step,
// 48 KB LDS traffic/step (16 KB stage + 32 KB ds_read; 2x2 wave-tiling reads
// every element twice) = ~95% of the 85 B/cyc ds_read_b128 ceiling -> ffn2 is
// LDS-BW-bound. Fix without growing the block tile: same 64x64 block, but
// each K-step is computed by ONE wave (rotating owner) holding a full 64x64
// acc[4][4] over its K-share -> each LDS element read exactly ONCE (reads
// halve: 32->16 KB/step). Partials reduced through LDS (as/bs reused as f32
// scratch, 3 serial rounds, ~96 KB/block extra = ~6%). Grid/staging/swizzle
// unchanged. k_pre/k_perm/k_f1c2 identical to R13.

typedef unsigned short u16;
typedef unsigned int u32;
typedef __bf16 bf16x8 __attribute__((ext_vector_type(8)));
typedef u16 u16x8 __attribute__((ext_vector_type(8)));
typedef float f32x4 __attribute__((ext_vector_type(4)));

#define N_TOK 16384
#define DIM   512
#define FDIM  2048
#define NEXP  8

__device__ inline u16 f2bf(float f) {
    u32 u = __float_as_uint(f);
    u = (u + 0x7FFF + ((u >> 16) & 1)) >> 16;  // RNE
    return (u16)u;
}

__device__ inline void gload16(const u16* g, u16* l) {
    __builtin_amdgcn_global_load_lds(
        (const __attribute__((address_space(1))) u32*)g,
        (__attribute__((address_space(3))) u32*)l, 16, 0, 0);
}

// Walk counts -> (expert, row0, rows) for 64-row m-slot `ms` (<=263 slots).
__device__ inline bool decode_ms64(const int* __restrict__ counts, int ms,
                                   int& e, int& row0, int& rows) {
    int t = 0, s = 0;
    for (int ee = 0; ee < NEXP; ++ee) {
        int c = counts[ee];
        int ntile = (c + 63) >> 6;
        if (ms < t + ntile) {
            int r = (ms - t) << 6;
            e = ee; row0 = s + r; rows = (c - r < 64) ? (c - r) : 64;
            return true;
        }
        t += ntile; s += c;
    }
    return false;
}

// ---------------- weight-conversion body (fp32 -> bf16 transposed) -----------
__device__ void wt_body(char* smem, int lb0, const float* __restrict__ W1,
                        const float* __restrict__ W2, u16* __restrict__ w1t,
                        u16* __restrict__ w2t) {
    float (*tile)[65] = (float(*)[65])smem;   // 64x65 fp32
    const int isW2 = lb0 >= 1024;
    const float* srcM = isW2 ? W2 : W1;
    u16* dstM = isW2 ? w2t : w1t;
    const int R = isW2 ? FDIM : DIM;
    const int C = isW2 ? DIM : FDIM;
    const int cT = C / 64;
    const int lb = isW2 ? lb0 - 1024 : lb0;
    for (int it = 0; it < 2; ++it) {
        const int gt = lb * 2 + it;
        const int e = gt >> 8;            // 256 tiles per expert-matrix
        const int rem = gt & 255;
        const int r0 = (rem / cT) * 64, c0 = (rem % cT) * 64;
        const float* s = srcM + (size_t)e * R * C;
        u16* d = dstM + (size_t)e * R * C;
        __syncthreads();
        const int lr = threadIdx.x >> 4;
        const int lc = (threadIdx.x & 15) * 4;
        for (int i = 0; i < 4; ++i) {
            int r = lr + i * 16;
            float4 v = *(const float4*)(s + (size_t)(r0 + r) * C + c0 + lc);
            tile[r][lc] = v.x; tile[r][lc + 1] = v.y;
            tile[r][lc + 2] = v.z; tile[r][lc + 3] = v.w;
        }
        __syncthreads();
        const int oc = threadIdx.x >> 3;
        const int orr = (threadIdx.x & 7) * 8;
        for (int p = 0; p < 2; ++p) {
            int c = oc + p * 32;
            u16x8 v;
            for (int j = 0; j < 8; ++j) v[j] = f2bf(tile[orr + j][c]);
            *(u16x8*)(d + (size_t)(c0 + c) * R + r0 + orr) = v;
        }
    }
}

__device__ void router_body(char* smem, int rb, const float* __restrict__ x,
                            const float* __restrict__ Wg, int* __restrict__ top1,
                            float* __restrict__ topval, int* __restrict__ pos,
                            int* __restrict__ counts, float* __restrict__ denom,
                            u16* __restrict__ xg) {
    float4* wgs4 = (float4*)smem;                       // 16 KB
    int*   lcnt   = (int*)(smem + 16384);
    float* lden   = (float*)(smem + 16384 + 32);
    int*   lbase  = (int*)(smem + 16384 + 64);
    int*   ltok_e = (int*)(smem + 16384 + 96);
    int*   ltok_r = (int*)(smem + 16384 + 224);
    const int tid = threadIdx.x;
    const int lane = tid & 63, wv = tid >> 6;
    for (int i = tid; i < NEXP * 128; i += 256) wgs4[i] = ((const float4*)Wg)[i];
    if (tid < NEXP) { lcnt[tid] = 0; lden[tid] = 0.f; }
    __syncthreads();
    const int tok0 = rb * 32;
    for (int tt = 0; tt < 8; ++tt) {
        const int tloc = wv * 8 + tt;
        const int n = tok0 + tloc;
        const float4* xr = (const float4*)(x + (size_t)n * DIM);
        float4 a = xr[lane], b = xr[64 + lane];
        // fused x -> bf16 cast (token order); replaces k_gather entirely
        {
            ushort4 va, vb;
            va.x = f2bf(a.x); va.y = f2bf(a.y); va.z = f2bf(a.z); va.w = f2bf(a.w);
            vb.x = f2bf(b.x); vb.y = f2bf(b.y); vb.z = f2bf(b.z); vb.w = f2bf(b.w);
            *(ushort4*)(xg + (size_t)n * DIM + 4 * lane) = va;
            *(ushort4*)(xg + (size_t)n * DIM + 256 + 4 * lane) = vb;
        }
        float p[NEXP];
#pragma unroll
        for (int e = 0; e < NEXP; ++e) {
            float4 wa = wgs4[e * 128 + lane], wb = wgs4[e * 128 + 64 + lane];
            p[e] = a.x * wa.x + a.y * wa.y + a.z * wa.z + a.w * wa.w
                 + b.x * wb.x + b.y * wb.y + b.z * wb.z + b.w * wb.w;
        }
#pragma unroll
        for (int e = 0; e < NEXP; ++e)
#pragma unroll
            for (int m = 32; m >= 1; m >>= 1)
                p[e] += __shfl_xor(p[e], m, 64);
        if (lane == 0) {
            float best = p[0]; int be = 0;
#pragma unroll
            for (int e = 1; e < NEXP; ++e)
                if (p[e] > best) { best = p[e]; be = e; }  // strict >: jnp.argmax
            top1[n] = be;
            topval[n] = best;
            ltok_e[tloc] = be;
            ltok_r[tloc] = atomicAdd(&lcnt[be], 1);
            atomicAdd(&lden[be], best);
        }
    }
    __syncthreads();
    if (tid < NEXP) {
        int c = lcnt[tid];
        lbase[tid] = c ? atomicAdd(&counts[tid], c) : 0;
        float dsum = lden[tid];
        if (dsum != 0.f) atomicAdd(&denom[tid], dsum);
    }
    __syncthreads();
    if (tid < 32) {
        int n = tok0 + tid;
        pos[n] = lbase[ltok_e[tid]] + ltok_r[tid];
    }
}

// ---------------- k_pre: router (0..511) | convW1 (512..1535) ----------------
__global__ __launch_bounds__(256) void k_pre(
    const float* __restrict__ W1, const float* __restrict__ W2,
    u16* __restrict__ w1t, u16* __restrict__ w2t,
    const float* __restrict__ x, const float* __restrict__ Wg,
    int* __restrict__ top1, float* __restrict__ topval,
    int* __restrict__ pos, int* __restrict__ counts, float* __restrict__ denom,
    u16* __restrict__ xg) {
    __shared__ __align__(16) char smem[16832];
    const int b = blockIdx.x;
    if (b < 512) router_body(smem, b, x, Wg, top1, topval, pos, counts, denom, xg);
    else wt_body(smem, b - 512, W1, W2, w1t, w2t);   // lb0 in [0,1024) -> W1
}

// ---------------- k_perm: sorted-slot -> token index -------------------------
__global__ __launch_bounds__(256) void k_perm(
    const int* __restrict__ top1, const int* __restrict__ pos,
    const int* __restrict__ counts, int* __restrict__ perm) {
    __shared__ int soffs[NEXP];
    if (threadIdx.x < NEXP) {
        int s = 0;
        for (int i = 0; i < (int)threadIdx.x; ++i) s += counts[i];
        soffs[threadIdx.x] = s;
    }
    __syncthreads();
    int n = blockIdx.x * 256 + threadIdx.x;
    perm[soffs[top1[n]] + pos[n]] = n;
}

// ---------- ffn1 body: hb = relu(x[perm] @ W1 + b1), tile 64x128x64 ----------
// 4352 blocks = 8 cx * 16 nt * 34 j; ms = cx + 8*j (64-row slots, XCD-affine).
__device__ void ffn1_body(
    char* smemc, int b,
    const u16* __restrict__ xg, const u16* __restrict__ w1t,
    const float* __restrict__ b1, const int* __restrict__ counts,
    const int* __restrict__ perm, u16* __restrict__ hb) {
    const int cx = b & 7;
    const int t = b >> 3;
    const int nt = t & 15;
    const int j = t >> 4;
    const int ms = cx + 8 * j;
    int e, row0, rows;
    if (!decode_ms64(counts, ms, e, row0, rows)) return;
    u16* as = (u16*)smemc;             // 64x64  = 8 KB
    u16* bs = (u16*)(smemc + 8192);    // 128x64 = 16 KB
    const int tid = threadIdx.x;
    const int lane = tid & 63, wid = tid >> 6;
    const int wr = wid >> 1, wc = wid & 1;
    const int q = lane >> 4, l15 = lane & 15;
    const int c = tid & 7;
    // hoisted perm lookups: each thread stages 2 fixed A-rows for all K-steps
    const int ra0 = tid >> 3;           // 0..31
    const int ra1 = 32 + (tid >> 3);    // 32..63
    const int tokA0 = perm[row0 + (ra0 < rows ? ra0 : rows - 1)];
    const int tokA1 = perm[row0 + (ra1 < rows ? ra1 : rows - 1)];
    const int gcA0 = (c ^ (ra0 & 7)) * 8;
    const int gcA1 = (c ^ (ra1 & 7)) * 8;
    const u16* B = w1t + (size_t)e * FDIM * DIM + (size_t)(nt * 128) * DIM;
    f32x4 acc[2][4];
#pragma unroll
    for (int i = 0; i < 2; ++i)
#pragma unroll
        for (int jj = 0; jj < 4; ++jj) acc[i][jj] = f32x4{0.f, 0.f, 0.f, 0.f};

    for (int k0 = 0; k0 < DIM; k0 += 64) {
        gload16(xg + (size_t)tokA0 * DIM + k0 + gcA0, as + tid * 8);
        gload16(xg + (size_t)tokA1 * DIM + k0 + gcA1, as + (256 + tid) * 8);
#pragma unroll
        for (int it = 0; it < 4; ++it) {
            int chunk = it * 256 + tid;
            int row = chunk >> 3;
            int gcol = c ^ (row & 7);
            gload16(B + (size_t)row * DIM + k0 + gcol * 8, bs + chunk * 8);
        }
        __syncthreads();
#pragma unroll
        for (int ks = 0; ks < 64; ks += 32) {
            bf16x8 af[2], bfr[4];
#pragma unroll
            for (int mi = 0; mi < 2; ++mi) {
                int m = wr * 32 + mi * 16 + l15;
                int cc = ((ks >> 3) + q) ^ (m & 7);
                af[mi] = *(const bf16x8*)(as + m * 64 + cc * 8);
            }
#pragma unroll
            for (int ni = 0; ni < 4; ++ni) {
                int n = wc * 64 + ni * 16 + l15;
                int cc = ((ks >> 3) + q) ^ (n & 7);
                bfr[ni] = *(const bf16x8*)(bs + n * 64 + cc * 8);
            }
#pragma unroll
            for (int mi = 0; mi < 2; ++mi)
#pragma unroll
                for (int ni = 0; ni < 4; ++ni)
                    acc[mi][ni] = __builtin_amdgcn_mfma_f32_16x16x32_bf16(
                        af[mi], bfr[ni], acc[mi][ni], 0, 0, 0);
        }
        __syncthreads();
    }
    const float* b1e = b1 + e * FDIM + nt * 128;
    float bcol[4];
#pragma unroll
    for (int ni = 0; ni < 4; ++ni) bcol[ni] = b1e[wc * 64 + ni * 16 + l15];
#pragma unroll
    for (int mi = 0; mi < 2; ++mi) {
#pragma unroll
        for (int r = 0; r < 4; ++r) {
            int mrow = wr * 32 + mi * 16 + q * 4 + r;
            if (mrow >= rows) continue;
            size_t base = (size_t)(row0 + mrow) * FDIM + nt * 128;
#pragma unroll
            for (int ni = 0; ni < 4; ++ni) {
                float v = acc[mi][ni][r] + bcol[ni];
                v = v > 0.f ? v : 0.f;
                hb[base + wc * 64 + ni * 16 + l15] = f2bf(v);
            }
        }
    }
}

// ---------------- k_f1c2: convW2 (0..1023, scheduled first) | ffn1 -----------
// conv blocks are short + HBM-bound; they overlap ffn1's MFMA phase instead
// of serializing in k_pre. ffn1 blocks are 1024..5375 (b' = b - 1024).
__global__ __launch_bounds__(256) void k_f1c2(
    const float* __restrict__ W1, const float* __restrict__ W2,
    u16* __restrict__ w1t, u16* __restrict__ w2t,
    const u16* __restrict__ xg, const float* __restrict__ b1,
    const int* __restrict__ counts, const int* __restrict__ perm,
    u16* __restrict__ hb) {
    __shared__ __align__(16) char smem[24576];
    const int b = blockIdx.x;
    if (b < 1024) wt_body(smem, 1024 + b, W1, W2, w1t, w2t);   // -> W2
    else ffn1_body(smem, b - 1024, xg, w1t, b1, counts, perm, hb);
}

// ---------------- GEMM2: out[tok] = gate*(hb @ W2 + b2), tile 64x64, splitK --
// grid 2176 = 8 cx * 8 nt * 34 j; ms = cx + 8*j (64-row slots, XCD-affine).
// R14: split-K across the 4 waves. Rotating owner wave ((k0>>6)&3) computes
// the whole 64x64 tile for its K-step into acc[4][4]; every LDS element is
// read exactly once (reads 32->16 KB/step; was 2x via 2x2 wave-tiling).
// Partials reduced through LDS (as/bs reused as 16 KB f32 scratch, 3 rounds);
// wave 0 applies bias+gate and stores.
__global__ __launch_bounds__(256) void k_ffn2(
    const u16* __restrict__ hb, const u16* __restrict__ w2t,
    const float* __restrict__ b2, const int* __restrict__ counts,
    const int* __restrict__ perm, const float* __restrict__ topval,
    const float* __restrict__ denom, float* __restrict__ out) {
    const int b = blockIdx.x;
    const int cx = b & 7;
    const int t = b >> 3;
    const int nt = t & 7;
    const int j = t >> 3;
    const int ms = cx + 8 * j;
    int e, row0, rows;
    if (!decode_ms64(counts, ms, e, row0, rows)) return;
    const float scale = 16384.0f / (denom[e] + 1e-6f);
    __shared__ __align__(16) u16 smem2[8192];   // as | bs ; reused as f32 scratch
    u16* as = smem2;           // 64x64 = 8 KB
    u16* bs = smem2 + 4096;    // 64x64 = 8 KB
    const u16* B = w2t + (size_t)e * DIM * FDIM + (size_t)(nt * 64) * FDIM;
    const int tid = threadIdx.x;
    const int lane = tid & 63, wid = tid >> 6;
    const int q = lane >> 4, l15 = lane & 15;
    const int c = tid & 7;
    f32x4 acc[4][4];   // full 64x64 per wave (its own K-share)
#pragma unroll
    for (int i = 0; i < 4; ++i)
#pragma unroll
        for (int jj = 0; jj < 4; ++jj) acc[i][jj] = f32x4{0.f, 0.f, 0.f, 0.f};

    for (int k0 = 0; k0 < FDIM; k0 += 64) {
#pragma unroll
        for (int it = 0; it < 2; ++it) {
            int chunk = it * 256 + tid;
            int row = chunk >> 3;
            int gcol = c ^ (row & 7);
            int rr = row < rows ? row : rows - 1;
            gload16(hb + (size_t)(row0 + rr) * FDIM + k0 + gcol * 8, as + chunk * 8);
        }
#pragma unroll
        for (int it = 0; it < 2; ++it) {
            int chunk = it * 256 + tid;
            int row = chunk >> 3;
            int gcol = c ^ (row & 7);
            gload16(B + (size_t)row * FDIM + k0 + gcol * 8, bs + chunk * 8);
        }
        __syncthreads();
        if (((k0 >> 6) & 3) == wid) {   // owner wave computes this K-step
#pragma unroll
            for (int ks = 0; ks < 64; ks += 32) {
                bf16x8 af[4], bfr[4];
#pragma unroll
                for (int mi = 0; mi < 4; ++mi) {
                    int m = mi * 16 + l15;
                    int cc = ((ks >> 3) + q) ^ (m & 7);
                    af[mi] = *(const bf16x8*)(as + m * 64 + cc * 8);
                }
#pragma unroll
                for (int ni = 0; ni < 4; ++ni) {
                    int n = ni * 16 + l15;
                    int cc = ((ks >> 3) + q) ^ (n & 7);
                    bfr[ni] = *(const bf16x8*)(bs + n * 64 + cc * 8);
                }
#pragma unroll
                for (int mi = 0; mi < 4; ++mi)
#pragma unroll
                    for (int ni = 0; ni < 4; ++ni)
                        acc[mi][ni] = __builtin_amdgcn_mfma_f32_16x16x32_bf16(
                            af[mi], bfr[ni], acc[mi][ni], 0, 0, 0);
            }
        }
        __syncthreads();
    }
    // ---- cross-wave reduction: waves 1..3 -> scratch, wave 0 accumulates ----
    float* scr = (float*)smem2;   // 4096 f32 = 16 KB (lane-contiguous b128)
#pragma unroll 1
    for (int w = 1; w < 4; ++w) {
        if (wid == w) {
#pragma unroll
            for (int f = 0; f < 16; ++f)
                *(f32x4*)(scr + (f * 64 + lane) * 4) = acc[f >> 2][f & 3];
        }
        __syncthreads();
        if (wid == 0) {
#pragma unroll
            for (int f = 0; f < 16; ++f) {
                f32x4 v = *(const f32x4*)(scr + (f * 64 + lane) * 4);
                acc[f >> 2][f & 3] += v;
            }
        }
        __syncthreads();
    }
    if (wid == 0) {
        float bcol[4];
#pragma unroll
        for (int ni = 0; ni < 4; ++ni)
            bcol[ni] = b2[e * DIM + nt * 64 + ni * 16 + l15];
#pragma unroll
        for (int mi = 0; mi < 4; ++mi) {
#pragma unroll
            for (int r = 0; r < 4; ++r) {
                int mrow = mi * 16 + q * 4 + r;
                if (mrow >= rows) continue;
                int tok = perm[row0 + mrow];
                float g = topval[tok] * scale;
                size_t base = (size_t)tok * DIM + nt * 64;
#pragma unroll
                for (int ni = 0; ni < 4; ++ni) {
                    float v = acc[mi][ni][r] + bcol[ni];
                    out[base + ni * 16 + l15] = g * v;
                }
            }
        }
    }
}

extern "C" void kernel_launch(void* const* d_in, const int* in_sizes, int n_in,
                              void* d_out, int out_size, void* d_ws, size_t ws_size,
                              hipStream_t stream) {
    const float* x  = (const float*)d_in[0];
    const float* Wg = (const float*)d_in[1];
    const float* W1 = (const float*)d_in[2];
    const float* b1 = (const float*)d_in[3];
    const float* W2 = (const float*)d_in[4];
    const float* b2 = (const float*)d_in[5];
    float* out = (float*)d_out;

    char* W = (char*)d_ws;
    int*   counts = (int*)W;                // 8 ints
    float* denom  = (float*)(W + 64);       // 8 floats
    int*   top1   = (int*)(W + 4096);
    float* topval = (float*)(W + 4096 + 65536);
    int*   pos    = (int*)(W + 4096 + 131072);
    int*   perm   = (int*)(W + 4096 + 196608);
    u16*   xg     = (u16*)(W + 266240);                  // N*D bf16 (token order)
    u16*   w1t    = xg  + (size_t)N_TOK * DIM;           // E*F*D bf16
    u16*   w2t    = w1t + (size_t)NEXP * FDIM * DIM;     // E*D*F bf16
    u16*   hb     = w2t + (size_t)NEXP * DIM * FDIM;     // N*F bf16 (sorted)

    hipMemsetAsync(W, 0, 128, stream);  // counts + denom
    k_pre<<<1536, 256, 0, stream>>>(W1, W2, w1t, w2t, x, Wg, top1, topval, pos,
                                    counts, denom, xg);
    k_perm<<<N_TOK / 256, 256, 0, stream>>>(top1, pos, counts, perm);
    k_f1c2<<<5376, 256, 0, stream>>>(W1, W2, w1t, w2t, xg, b1, counts, perm, hb);
    k_ffn2<<<2176, 256, 0, stream>>>(hb, w2t, b2, counts, perm, topval, denom, out);
}

// Round 9
// 263.041 us; speedup vs baseline: 1.1839x; 1.1839x over previous
//
#include <hip/hip_runtime.h>
#include <hip/hip_bf16.h>

// SwitchMoE: N=16384, D=512, F=2048, E=8, top-1. Sparse one-expert-per-token.
// R15: revert ffn2 to R13's measured-best 64x64 config (R14's split-K
// serialized MFMA across waves: 1-of-4 waves computing per barrier-locked
// step -> 115us; LDS-byte model was right, wave-parallelism constraint was
// missing). ffn2 ~66us = practical floor for the LDS-staged structure
// (82 B/cyc/CU ~ ds_read_b128 ceiling). New lever: the dispatch ledger --
// k_f1c2 66 + k_ffn2 66 + k_pre ~25 + k_perm ~4 leaves ~100us of serial
// dispatch gaps in the 263us total. Remove one dispatch: router scatters the
// permutation DIRECTLY into per-expert-strided perm2[e*16384+rank] (it knows
// expert+rank already); decode_ms64 returns the within-expert offset so the
// GEMMs index perm2 without the global scan. k_perm, pos[], top1[] deleted.

typedef unsigned short u16;
typedef unsigned int u32;
typedef __bf16 bf16x8 __attribute__((ext_vector_type(8)));
typedef u16 u16x8 __attribute__((ext_vector_type(8)));
typedef float f32x4 __attribute__((ext_vector_type(4)));

#define N_TOK 16384
#define DIM   512
#define FDIM  2048
#define NEXP  8

__device__ inline u16 f2bf(float f) {
    u32 u = __float_as_uint(f);
    u = (u + 0x7FFF + ((u >> 16) & 1)) >> 16;  // RNE
    return (u16)u;
}

__device__ inline void gload16(const u16* g, u16* l) {
    __builtin_amdgcn_global_load_lds(
        (const __attribute__((address_space(1))) u32*)g,
        (__attribute__((address_space(3))) u32*)l, 16, 0, 0);
}

// Walk counts -> (expert, row0 global-sorted, rloc within-expert, rows)
// for 64-row m-slot `ms` (<=263 slots).
__device__ inline bool decode_ms64(const int* __restrict__ counts, int ms,
                                   int& e, int& row0, int& rloc, int& rows) {
    int t = 0, s = 0;
    for (int ee = 0; ee < NEXP; ++ee) {
        int c = counts[ee];
        int ntile = (c + 63) >> 6;
        if (ms < t + ntile) {
            int r = (ms - t) << 6;
            e = ee; row0 = s + r; rloc = r; rows = (c - r < 64) ? (c - r) : 64;
            return true;
        }
        t += ntile; s += c;
    }
    return false;
}

// ---------------- weight-conversion body (fp32 -> bf16 transposed) -----------
__device__ void wt_body(char* smem, int lb0, const float* __restrict__ W1,
                        const float* __restrict__ W2, u16* __restrict__ w1t,
                        u16* __restrict__ w2t) {
    float (*tile)[65] = (float(*)[65])smem;   // 64x65 fp32
    const int isW2 = lb0 >= 1024;
    const float* srcM = isW2 ? W2 : W1;
    u16* dstM = isW2 ? w2t : w1t;
    const int R = isW2 ? FDIM : DIM;
    const int C = isW2 ? DIM : FDIM;
    const int cT = C / 64;
    const int lb = isW2 ? lb0 - 1024 : lb0;
    for (int it = 0; it < 2; ++it) {
        const int gt = lb * 2 + it;
        const int e = gt >> 8;            // 256 tiles per expert-matrix
        const int rem = gt & 255;
        const int r0 = (rem / cT) * 64, c0 = (rem % cT) * 64;
        const float* s = srcM + (size_t)e * R * C;
        u16* d = dstM + (size_t)e * R * C;
        __syncthreads();
        const int lr = threadIdx.x >> 4;
        const int lc = (threadIdx.x & 15) * 4;
        for (int i = 0; i < 4; ++i) {
            int r = lr + i * 16;
            float4 v = *(const float4*)(s + (size_t)(r0 + r) * C + c0 + lc);
            tile[r][lc] = v.x; tile[r][lc + 1] = v.y;
            tile[r][lc + 2] = v.z; tile[r][lc + 3] = v.w;
        }
        __syncthreads();
        const int oc = threadIdx.x >> 3;
        const int orr = (threadIdx.x & 7) * 8;
        for (int p = 0; p < 2; ++p) {
            int c = oc + p * 32;
            u16x8 v;
            for (int j = 0; j < 8; ++j) v[j] = f2bf(tile[orr + j][c]);
            *(u16x8*)(d + (size_t)(c0 + c) * R + r0 + orr) = v;
        }
    }
}

__device__ void router_body(char* smem, int rb, const float* __restrict__ x,
                            const float* __restrict__ Wg,
                            float* __restrict__ topval,
                            int* __restrict__ counts, float* __restrict__ denom,
                            int* __restrict__ perm2, u16* __restrict__ xg) {
    float4* wgs4 = (float4*)smem;                       // 16 KB
    int*   lcnt   = (int*)(smem + 16384);
    float* lden   = (float*)(smem + 16384 + 32);
    int*   lbase  = (int*)(smem + 16384 + 64);
    int*   ltok_e = (int*)(smem + 16384 + 96);
    int*   ltok_r = (int*)(smem + 16384 + 224);
    const int tid = threadIdx.x;
    const int lane = tid & 63, wv = tid >> 6;
    for (int i = tid; i < NEXP * 128; i += 256) wgs4[i] = ((const float4*)Wg)[i];
    if (tid < NEXP) { lcnt[tid] = 0; lden[tid] = 0.f; }
    __syncthreads();
    const int tok0 = rb * 32;
    for (int tt = 0; tt < 8; ++tt) {
        const int tloc = wv * 8 + tt;
        const int n = tok0 + tloc;
        const float4* xr = (const float4*)(x + (size_t)n * DIM);
        float4 a = xr[lane], b = xr[64 + lane];
        // fused x -> bf16 cast (token order); replaces k_gather entirely
        {
            ushort4 va, vb;
            va.x = f2bf(a.x); va.y = f2bf(a.y); va.z = f2bf(a.z); va.w = f2bf(a.w);
            vb.x = f2bf(b.x); vb.y = f2bf(b.y); vb.z = f2bf(b.z); vb.w = f2bf(b.w);
            *(ushort4*)(xg + (size_t)n * DIM + 4 * lane) = va;
            *(ushort4*)(xg + (size_t)n * DIM + 256 + 4 * lane) = vb;
        }
        float p[NEXP];
#pragma unroll
        for (int e = 0; e < NEXP; ++e) {
            float4 wa = wgs4[e * 128 + lane], wb = wgs4[e * 128 + 64 + lane];
            p[e] = a.x * wa.x + a.y * wa.y + a.z * wa.z + a.w * wa.w
                 + b.x * wb.x + b.y * wb.y + b.z * wb.z + b.w * wb.w;
        }
#pragma unroll
        for (int e = 0; e < NEXP; ++e)
#pragma unroll
            for (int m = 32; m >= 1; m >>= 1)
                p[e] += __shfl_xor(p[e], m, 64);
        if (lane == 0) {
            float best = p[0]; int be = 0;
#pragma unroll
            for (int e = 1; e < NEXP; ++e)
                if (p[e] > best) { best = p[e]; be = e; }  // strict >: jnp.argmax
            topval[n] = best;
            ltok_e[tloc] = be;
            ltok_r[tloc] = atomicAdd(&lcnt[be], 1);
            atomicAdd(&lden[be], best);
        }
    }
    __syncthreads();
    if (tid < NEXP) {
        int c = lcnt[tid];
        lbase[tid] = c ? atomicAdd(&counts[tid], c) : 0;
        float dsum = lden[tid];
        if (dsum != 0.f) atomicAdd(&denom[tid], dsum);
    }
    __syncthreads();
    if (tid < 32) {
        int eh = ltok_e[tid];
        perm2[eh * N_TOK + lbase[eh] + ltok_r[tid]] = tok0 + tid;
    }
}

// ---------------- k_pre: router (0..511) | convW1 (512..1535) ----------------
__global__ __launch_bounds__(256) void k_pre(
    const float* __restrict__ W1, const float* __restrict__ W2,
    u16* __restrict__ w1t, u16* __restrict__ w2t,
    const float* __restrict__ x, const float* __restrict__ Wg,
    float* __restrict__ topval,
    int* __restrict__ counts, float* __restrict__ denom,
    int* __restrict__ perm2, u16* __restrict__ xg) {
    __shared__ __align__(16) char smem[16832];
    const int b = blockIdx.x;
    if (b < 512) router_body(smem, b, x, Wg, topval, counts, denom, perm2, xg);
    else wt_body(smem, b - 512, W1, W2, w1t, w2t);   // lb0 in [0,1024) -> W1
}

// ---------- ffn1 body: hb = relu(x[perm] @ W1 + b1), tile 64x128x64 ----------
// 4352 blocks = 8 cx * 16 nt * 34 j; ms = cx + 8*j (64-row slots, XCD-affine).
__device__ void ffn1_body(
    char* smemc, int b,
    const u16* __restrict__ xg, const u16* __restrict__ w1t,
    const float* __restrict__ b1, const int* __restrict__ counts,
    const int* __restrict__ perm2, u16* __restrict__ hb) {
    const int cx = b & 7;
    const int t = b >> 3;
    const int nt = t & 15;
    const int j = t >> 4;
    const int ms = cx + 8 * j;
    int e, row0, rloc, rows;
    if (!decode_ms64(counts, ms, e, row0, rloc, rows)) return;
    u16* as = (u16*)smemc;             // 64x64  = 8 KB
    u16* bs = (u16*)(smemc + 8192);    // 128x64 = 16 KB
    const int tid = threadIdx.x;
    const int lane = tid & 63, wid = tid >> 6;
    const int wr = wid >> 1, wc = wid & 1;
    const int q = lane >> 4, l15 = lane & 15;
    const int c = tid & 7;
    // hoisted perm lookups: each thread stages 2 fixed A-rows for all K-steps
    const int ra0 = tid >> 3;           // 0..31
    const int ra1 = 32 + (tid >> 3);    // 32..63
    const int* pe = perm2 + (size_t)e * N_TOK + rloc;
    const int tokA0 = pe[ra0 < rows ? ra0 : rows - 1];
    const int tokA1 = pe[ra1 < rows ? ra1 : rows - 1];
    const int gcA0 = (c ^ (ra0 & 7)) * 8;
    const int gcA1 = (c ^ (ra1 & 7)) * 8;
    const u16* B = w1t + (size_t)e * FDIM * DIM + (size_t)(nt * 128) * DIM;
    f32x4 acc[2][4];
#pragma unroll
    for (int i = 0; i < 2; ++i)
#pragma unroll
        for (int jj = 0; jj < 4; ++jj) acc[i][jj] = f32x4{0.f, 0.f, 0.f, 0.f};

    for (int k0 = 0; k0 < DIM; k0 += 64) {
        gload16(xg + (size_t)tokA0 * DIM + k0 + gcA0, as + tid * 8);
        gload16(xg + (size_t)tokA1 * DIM + k0 + gcA1, as + (256 + tid) * 8);
#pragma unroll
        for (int it = 0; it < 4; ++it) {
            int chunk = it * 256 + tid;
            int row = chunk >> 3;
            int gcol = c ^ (row & 7);
            gload16(B + (size_t)row * DIM + k0 + gcol * 8, bs + chunk * 8);
        }
        __syncthreads();
#pragma unroll
        for (int ks = 0; ks < 64; ks += 32) {
            bf16x8 af[2], bfr[4];
#pragma unroll
            for (int mi = 0; mi < 2; ++mi) {
                int m = wr * 32 + mi * 16 + l15;
                int cc = ((ks >> 3) + q) ^ (m & 7);
                af[mi] = *(const bf16x8*)(as + m * 64 + cc * 8);
            }
#pragma unroll
            for (int ni = 0; ni < 4; ++ni) {
                int n = wc * 64 + ni * 16 + l15;
                int cc = ((ks >> 3) + q) ^ (n & 7);
                bfr[ni] = *(const bf16x8*)(bs + n * 64 + cc * 8);
            }
#pragma unroll
            for (int mi = 0; mi < 2; ++mi)
#pragma unroll
                for (int ni = 0; ni < 4; ++ni)
                    acc[mi][ni] = __builtin_amdgcn_mfma_f32_16x16x32_bf16(
                        af[mi], bfr[ni], acc[mi][ni], 0, 0, 0);
        }
        __syncthreads();
    }
    const float* b1e = b1 + e * FDIM + nt * 128;
    float bcol[4];
#pragma unroll
    for (int ni = 0; ni < 4; ++ni) bcol[ni] = b1e[wc * 64 + ni * 16 + l15];
#pragma unroll
    for (int mi = 0; mi < 2; ++mi) {
#pragma unroll
        for (int r = 0; r < 4; ++r) {
            int mrow = wr * 32 + mi * 16 + q * 4 + r;
            if (mrow >= rows) continue;
            size_t base = (size_t)(row0 + mrow) * FDIM + nt * 128;
#pragma unroll
            for (int ni = 0; ni < 4; ++ni) {
                float v = acc[mi][ni][r] + bcol[ni];
                v = v > 0.f ? v : 0.f;
                hb[base + wc * 64 + ni * 16 + l15] = f2bf(v);
            }
        }
    }
}

// ---------------- k_f1c2: convW2 (0..1023, scheduled first) | ffn1 -----------
// conv blocks are short + HBM-bound; they overlap ffn1's MFMA phase instead
// of serializing in k_pre. ffn1 blocks are 1024..5375 (b' = b - 1024).
__global__ __launch_bounds__(256) void k_f1c2(
    const float* __restrict__ W1, const float* __restrict__ W2,
    u16* __restrict__ w1t, u16* __restrict__ w2t,
    const u16* __restrict__ xg, const float* __restrict__ b1,
    const int* __restrict__ counts, const int* __restrict__ perm2,
    u16* __restrict__ hb) {
    __shared__ __align__(16) char smem[24576];
    const int b = blockIdx.x;
    if (b < 1024) wt_body(smem, 1024 + b, W1, W2, w1t, w2t);   // -> W2
    else ffn1_body(smem, b - 1024, xg, w1t, b1, counts, perm2, hb);
}

// ---------------- GEMM2: out[tok] = gate*(hb @ W2 + b2), tile 64x64x64 -------
// grid 2176 = 8 cx * 8 nt * 34 j; ms = cx + 8*j (64-row slots, XCD-affine:
// same-slot nt-blocks are 8 apart -> same XCD -> hb A-tile L2 reuse). LDS
// 16 KB, acc[2][2]: ~8 resident blocks/CU; measured-best config (R7/R13,
// ~66us; 82 B/cyc/CU LDS traffic ~ ds_read_b128 ceiling = structural floor).
__global__ __launch_bounds__(256) void k_ffn2(
    const u16* __restrict__ hb, const u16* __restrict__ w2t,
    const float* __restrict__ b2, const int* __restrict__ counts,
    const int* __restrict__ perm2, const float* __restrict__ topval,
    const float* __restrict__ denom, float* __restrict__ out) {
    const int b = blockIdx.x;
    const int cx = b & 7;
    const int t = b >> 3;
    const int nt = t & 7;
    const int j = t >> 3;
    const int ms = cx + 8 * j;
    int e, row0, rloc, rows;
    if (!decode_ms64(counts, ms, e, row0, rloc, rows)) return;
    const float scale = 16384.0f / (denom[e] + 1e-6f);
    __shared__ u16 as[64 * 64];    // 8 KB
    __shared__ u16 bs[64 * 64];    // 8 KB
    const u16* B = w2t + (size_t)e * DIM * FDIM + (size_t)(nt * 64) * FDIM;
    const int* pe = perm2 + (size_t)e * N_TOK + rloc;
    const int tid = threadIdx.x;
    const int lane = tid & 63, wid = tid >> 6;
    const int wr = wid >> 1, wc = wid & 1;
    const int q = lane >> 4, l15 = lane & 15;
    const int c = tid & 7;
    f32x4 acc[2][2];
#pragma unroll
    for (int i = 0; i < 2; ++i)
#pragma unroll
        for (int jj = 0; jj < 2; ++jj) acc[i][jj] = f32x4{0.f, 0.f, 0.f, 0.f};

    for (int k0 = 0; k0 < FDIM; k0 += 64) {
#pragma unroll
        for (int it = 0; it < 2; ++it) {
            int chunk = it * 256 + tid;
            int row = chunk >> 3;
            int gcol = c ^ (row & 7);
            int rr = row < rows ? row : rows - 1;
            gload16(hb + (size_t)(row0 + rr) * FDIM + k0 + gcol * 8, as + chunk * 8);
        }
#pragma unroll
        for (int it = 0; it < 2; ++it) {
            int chunk = it * 256 + tid;
            int row = chunk >> 3;
            int gcol = c ^ (row & 7);
            gload16(B + (size_t)row * FDIM + k0 + gcol * 8, bs + chunk * 8);
        }
        __syncthreads();
#pragma unroll
        for (int ks = 0; ks < 64; ks += 32) {
            bf16x8 af[2], bfr[2];
#pragma unroll
            for (int mi = 0; mi < 2; ++mi) {
                int m = wr * 32 + mi * 16 + l15;
                int cc = ((ks >> 3) + q) ^ (m & 7);
                af[mi] = *(const bf16x8*)(as + m * 64 + cc * 8);
            }
#pragma unroll
            for (int ni = 0; ni < 2; ++ni) {
                int n = wc * 32 + ni * 16 + l15;
                int cc = ((ks >> 3) + q) ^ (n & 7);
                bfr[ni] = *(const bf16x8*)(bs + n * 64 + cc * 8);
            }
#pragma unroll
            for (int mi = 0; mi < 2; ++mi)
#pragma unroll
                for (int ni = 0; ni < 2; ++ni)
                    acc[mi][ni] = __builtin_amdgcn_mfma_f32_16x16x32_bf16(
                        af[mi], bfr[ni], acc[mi][ni], 0, 0, 0);
        }
        __syncthreads();
    }
    float bcol[2];
#pragma unroll
    for (int ni = 0; ni < 2; ++ni)
        bcol[ni] = b2[e * DIM + nt * 64 + wc * 32 + ni * 16 + l15];
#pragma unroll
    for (int mi = 0; mi < 2; ++mi) {
#pragma unroll
        for (int r = 0; r < 4; ++r) {
            int mrow = wr * 32 + mi * 16 + q * 4 + r;
            if (mrow >= rows) continue;
            int tok = pe[mrow];
            float g = topval[tok] * scale;
            size_t base = (size_t)tok * DIM + nt * 64;
#pragma unroll
            for (int ni = 0; ni < 2; ++ni) {
                float v = acc[mi][ni][r] + bcol[ni];
                out[base + wc * 32 + ni * 16 + l15] = g * v;
            }
        }
    }
}

extern "C" void kernel_launch(void* const* d_in, const int* in_sizes, int n_in,
                              void* d_out, int out_size, void* d_ws, size_t ws_size,
                              hipStream_t stream) {
    const float* x  = (const float*)d_in[0];
    const float* Wg = (const float*)d_in[1];
    const float* W1 = (const float*)d_in[2];
    const float* b1 = (const float*)d_in[3];
    const float* W2 = (const float*)d_in[4];
    const float* b2 = (const float*)d_in[5];
    float* out = (float*)d_out;

    char* W = (char*)d_ws;
    int*   counts = (int*)W;                       // 8 ints
    float* denom  = (float*)(W + 64);              // 8 floats
    float* topval = (float*)(W + 4096);            // N floats (64 KB)
    int*   perm2  = (int*)(W + 69632);             // E*N ints (512 KB)
    u16*   xg     = (u16*)(W + 593920);            // N*D bf16 (token order)
    u16*   w1t    = xg  + (size_t)N_TOK * DIM;     // E*F*D bf16
    u16*   w2t    = w1t + (size_t)NEXP * FDIM * DIM;  // E*D*F bf16
    u16*   hb     = w2t + (size_t)NEXP * DIM * FDIM;  // N*F bf16 (sorted)

    hipMemsetAsync(W, 0, 128, stream);  // counts + denom
    k_pre<<<1536, 256, 0, stream>>>(W1, W2, w1t, w2t, x, Wg, topval,
                                    counts, denom, perm2, xg);
    k_f1c2<<<5376, 256, 0, stream>>>(W1, W2, w1t, w2t, xg, b1, counts, perm2, hb);
    k_ffn2<<<2176, 256, 0, stream>>>(hb, w2t, b2, counts, perm2, topval, denom, out);
}